// Round 2
// baseline (165801.294 us; speedup 1.0000x reference)
//
#include <hip/hip_runtime.h>

typedef _Float16 f16;
typedef _Float16 f16x8 __attribute__((ext_vector_type(8)));
typedef float f32x4 __attribute__((ext_vector_type(4)));

#define T_STEPS 1024
#define BATCH 128
#define HID 512
#define VOC 65
#define LOC_D 2               // self-recurrence ring depth (h(t-1) only)
#define CRS_D 4               // cross-consumer ring depth

// ---- workspace layout (bytes) — total 15,123,456 < round-0's proven 15,909,888 ----
#define OFF_FLOCAL 0          // [6][32] intra-group flags (128B line per group)
#define OFF_FCROSS 1024       // [6][32] cross flags: FC=v => finished step v AND h(v-1) at coherence pt (init -1)
#define OFF_FPROJ  2048       // [20]    proj flags: FP=v => proj finished step v (init -1)
#define OFF_XCCS   2304       // [6][32] per-member XCC ids
#define OFF_RCNT   3072       // [6]     rendezvous counters
#define OFF_TEST   3200       // [6][32] sc0 ping-pong scratch (never reused afterward)
#define OFF_VOTE   4096       // [6][32] fast/slow votes (0=unset,1=slow,2=fast)
#define OFF_HRING  32768                              // local ring [3][2][128][512] f16
#define HLOC_BYTES (3*LOC_D*BATCH*HID*2)              // 786,432
#define OFF_CROSS  (OFF_HRING + HLOC_BYTES)           // cross ring [3][4][128][512] f16
#define HCRS_BYTES (3*CRS_D*BATCH*HID*2)              // 1,572,864
#define OFF_WPACK  (OFF_CROSS + HCRS_BYTES)           // 2,392,064
#define WPACK_BYTES (3*32*65536*2)                    // 12,582,912
#define OFF_WOUT   (OFF_WPACK + WPACK_BYTES)          // 14,974,976
#define WOUT_BYTES (5*16*512*2)                       // 81,920
#define OFF_EMB    (OFF_WOUT + WOUT_BYTES)            // 15,056,896 (+66,560 emb)

__device__ __forceinline__ float sigmoidf_(float x){ return 1.0f/(1.0f+__expf(-x)); }
__device__ __forceinline__ float tanhf_(float x){ return 1.0f - 2.0f/(__expf(2.0f*x)+1.0f); }

// coherence-point (cross-XCD) ops
__device__ __forceinline__ f16x8 ld16_sc(const f16* p) {
  f16x8 r;
  asm volatile("global_load_dwordx4 %0, %1, off sc0 sc1" : "=v"(r) : "v"(p) : "memory");
  return r;
}
__device__ __forceinline__ void st16_sc1(f16* p, f16x8 v){
  asm volatile("global_store_dwordx4 %0, %1, off sc1"::"v"(p),"v"(v):"memory"); }
// XCD-local (shared L2) ops: bypass L1 only
__device__ __forceinline__ f16x8 ld16_l2(const f16* p) {
  f16x8 r;
  asm volatile("global_load_dwordx4 %0, %1, off sc0" : "=v"(r) : "v"(p) : "memory");
  return r;
}
__device__ __forceinline__ void st16_l2(f16* p, f16x8 v){
  asm volatile("global_store_dwordx4 %0, %1, off sc0"::"v"(p),"v"(v):"memory"); }
// flag ops (4B); loads embed their own wait
__device__ __forceinline__ int ld4_sc(const int* p){
  int r;
  asm volatile("global_load_dword %0, %1, off sc0 sc1\n\ts_waitcnt vmcnt(0)" : "=v"(r) : "v"(p) : "memory");
  return r;
}
__device__ __forceinline__ int ld4_l2(const int* p){
  int r;
  asm volatile("global_load_dword %0, %1, off sc0\n\ts_waitcnt vmcnt(0)" : "=v"(r) : "v"(p) : "memory");
  return r;
}
__device__ __forceinline__ void st4_sc1(int* p, int v){
  asm volatile("global_store_dword %0, %1, off sc1"::"v"(p),"v"(v):"memory"); }
__device__ __forceinline__ void st4_l2(int* p, int v){
  asm volatile("global_store_dword %0, %1, off sc0"::"v"(p),"v"(v):"memory"); }

// Pack weights FRAG-MAJOR (unchanged): per (l,g): 4 gate-tiles (r,z,n-hi,n-lo*2048) x 32 kc x [64 lanes x 8 f16].
// Also initializes cross/proj flags to -1 (memset runs before this kernel on the same stream).
__global__ void convert_kernel(const float* __restrict__ emb, const float* __restrict__ w_ih,
                               const float* __restrict__ w_hh, const float* __restrict__ w_out,
                               char* __restrict__ ws) {
  if (blockIdx.x == 0) {
    int* FCp = (int*)(ws + OFF_FCROSS);
    int* FPp = (int*)(ws + OFF_FPROJ);
    const int t0 = threadIdx.x;
    if (t0 < 192) FCp[t0] = -1;
    else if (t0 < 212) FPp[t0 - 192] = -1;
  }
  f16* wpack = (f16*)(ws + OFF_WPACK);
  f16* wout  = (f16*)(ws + OFF_WOUT);
  f16* embh  = (f16*)(ws + OFF_EMB);
  const int NW = 3*32*65536;
  const int TOT = NW + 40960 + VOC*HID;
  for (int e = blockIdx.x*blockDim.x + threadIdx.x; e < TOT; e += gridDim.x*blockDim.x) {
    if (e < NW) {
      int l = e >> 21, rem = e & 0x1FFFFF;
      int g = rem >> 16, idx = rem & 0xFFFF;
      int gt = idx >> 14, kc = (idx >> 9) & 31, lane = (idx >> 3) & 63, jj = idx & 7;
      int n = lane & 15, q = lane >> 4;
      int k = kc*32 + q*8 + jj, d = g*16 + n;
      int row = (gt==0) ? d : (gt==1) ? 512+d : 1024+d;
      float f = (k < 512) ? w_ih[((size_t)(l*1536+row)<<9) + k]
                          : w_hh[((size_t)(l*1536+row)<<9) + (k-512)];
      f16 h;
      if (gt < 3) h = (f16)f;
      else { f16 hi = (f16)f; h = (f16)((f - (float)hi)*2048.0f); }
      wpack[e] = h;
    } else if (e < NW + 40960) {
      int idx = e - NW;
      int vt = idx >> 13, r2 = idx & 8191;
      int kc = r2 >> 9, lane = (r2 >> 3) & 63, jj = r2 & 7;
      int n = lane & 15, q = lane >> 4;
      int v = vt*16 + n, k = kc*32 + q*8 + jj;
      wout[idx] = (v < VOC) ? (f16)w_out[((size_t)v<<9) + k] : (f16)0.0f;
    } else {
      int idx = e - NW - 40960;
      embh[idx] = (f16)emb[idx];
    }
  }
}

// One (layer,bh) group = 32 dim-slice WGs, runtime-verified same-XCD.
// FAST: self h + local flags via shared XCD L2 (sc0); cross copy written sc1 AFTER the local flag,
//       published one step deferred (FC=t at end of step t => h(t-1) remotely visible).
// SLOW: everything through the coherence point (placement-independent, round-0 protocol).
template<bool FAST>
__device__ __forceinline__ void layer_loop(const int l, const int bh, const int g,
    const int* __restrict__ xseq, const float* __restrict__ bias,
    const float* __restrict__ bias_n, char* __restrict__ ws,
    const f16* wlds, f16* hstage, int* s_bail)
{
  const int gid = l*2 + bh;
  const int tid = threadIdx.x;
  const int lane = tid & 63, wv = tid >> 6;
  const int quad = lane >> 4, ko = quad*8, nlane = lane & 15;
  int* FL = (int*)(ws + OFF_FLOCAL) + gid*32;
  int* FC = (int*)(ws + OFF_FCROSS);
  int* FP = (int*)(ws + OFF_FPROJ);
  f16* hloc = (f16*)(ws + OFF_HRING);
  f16* hcrs = (f16*)(ws + OFF_CROSS);
  const f16* embh = (const f16*)(ws + OFF_EMB);

  const int j = g*16 + nlane;
  const float br  = bias[l*1536 + j];
  const float bz  = bias[l*1536 + 512 + j];
  const float bin = bias[l*1536 + 1024 + j];
  const float bn  = bias_n[l*512 + j];
  const int bm = bh*64 + wv*16 + nlane;             // A-operand batch row

  // register-resident B-frags for r and z gates; conflict-free reads
  f16x8 wr[32], wz[32];
#pragma unroll
  for (int kc = 0; kc < 32; ++kc) {
    wr[kc] = *(const f16x8*)(wlds + (((0*32 + kc)*64 + lane) << 3));
    wz[kc] = *(const f16x8*)(wlds + (((1*32 + kc)*64 + lane) << 3));
  }
  unsigned short hprev[4] = {0, 0, 0, 0};

  for (int t = 0; t < T_STEPS; ++t) {
    // --- phase 1 polls: back-pressure (wv1) and cross-input readiness (wv2). Always coherence-point.
    if (wv == 1) {
      const int tgt = t - CRS_D;                 // overwriting cross slot t&3 kills h(t-4): need consumer finished t-4
      if (tgt >= 0) {
        const int m = lane & 31;
        const int cap = *s_bail ? (1<<8) : (1<<22);
        int spins = 0;
        while (1) {
          int v = 0x7FFFFFFF;
          if (l < 2) v = ld4_sc(FC + (gid+2)*32 + m);
          else if (m < 10) v = ld4_sc(FP + bh*10 + m);
          if (__all(v >= tgt)) break;
          if (++spins > cap) { *s_bail = 1; break; }
          __builtin_amdgcn_s_sleep(1);
        }
      }
    } else if (wv == 2 && l > 0) {
      const int m = lane & 31;                   // need h_{l-1}(t): FC >= t+1
      const int cap = *s_bail ? (1<<8) : (1<<22);
      int spins = 0;
      while (1) {
        int v = ld4_sc(FC + (gid-2)*32 + m);
        if (__all(v >= t + 1)) break;
        if (++spins > cap) { *s_bail = 1; break; }
        __builtin_amdgcn_s_sleep(1);
      }
    }
    __syncthreads();                             // B1: cross input ready

    // issue input loads now so their latency overlaps the local self-poll
    f16x8 afr[32];
    if (l == 0) {
      int idx = xseq[bm*T_STEPS + t];
      const f16* xr = embh + (size_t)idx*HID + ko;   // immutable: plain cached loads
#pragma unroll
      for (int kc = 0; kc < 16; ++kc) afr[kc] = *(const f16x8*)(xr + kc*32);
    } else {
      const f16* xr = hcrs + ((size_t)((l-1)*CRS_D + (t & (CRS_D-1)))*BATCH + bm)*HID + ko;
#pragma unroll
      for (int kc = 0; kc < 16; ++kc) afr[kc] = ld16_sc(xr + kc*32);
    }
    if (wv == 0) {                               // self h(t-1) ready: local flags >= t
      const int m = lane & 31;
      const int cap = *s_bail ? (1<<8) : (1<<22);
      int spins = 0;
      while (1) {
        int v = FAST ? ld4_l2(FL + m) : ld4_sc(FL + m);
        if (__all(v >= t)) break;
        if (++spins > cap) { *s_bail = 1; break; }
        __builtin_amdgcn_s_sleep(1);
      }
    }
    __syncthreads();                             // B2: self h(t-1) visible
    {
      const f16* hrk = FAST
        ? hloc + ((size_t)(l*LOC_D + ((t+1)&1))*BATCH + bm)*HID + ko
        : hcrs + ((size_t)(l*CRS_D + ((t+3)&3))*BATCH + bm)*HID + ko;
#pragma unroll
      for (int kc = 0; kc < 16; ++kc)
        afr[16 + kc] = FAST ? ld16_l2(hrk + kc*32) : ld16_sc(hrk + kc*32);
    }
    asm volatile("s_waitcnt vmcnt(0)" ::: "memory");   // also drains last step's deferred sc1 h stores
#pragma unroll
    for (int kc = 0; kc < 32; ++kc) asm volatile("" : "+v"(afr[kc]));

    f32x4 ar{0,0,0,0}, az{0,0,0,0}, anxh{0,0,0,0}, anxl{0,0,0,0}, anhh{0,0,0,0}, anhl{0,0,0,0};
#pragma unroll
    for (int kc = 0; kc < 32; ++kc) {
      f16x8 wnh = *(const f16x8*)(wlds + (((2*32 + kc)*64 + lane) << 3));
      f16x8 wnl = *(const f16x8*)(wlds + (((3*32 + kc)*64 + lane) << 3));
      ar = __builtin_amdgcn_mfma_f32_16x16x32_f16(afr[kc], wr[kc], ar, 0, 0, 0);
      az = __builtin_amdgcn_mfma_f32_16x16x32_f16(afr[kc], wz[kc], az, 0, 0, 0);
      if (kc < 16) {
        anxh = __builtin_amdgcn_mfma_f32_16x16x32_f16(afr[kc], wnh, anxh, 0, 0, 0);
        anxl = __builtin_amdgcn_mfma_f32_16x16x32_f16(afr[kc], wnl, anxl, 0, 0, 0);
      } else {
        anhh = __builtin_amdgcn_mfma_f32_16x16x32_f16(afr[kc], wnh, anhh, 0, 0, 0);
        anhl = __builtin_amdgcn_mfma_f32_16x16x32_f16(afr[kc], wnl, anhl, 0, 0, 0);
      }
    }
    // epilogue: D layout col(lane&15)=dim j, row_local(wv*16+quad*4+i)=batch (within bh half)
#pragma unroll
    for (int i = 0; i < 4; ++i) {
      float rr = sigmoidf_(ar[i] + br);
      float zz = sigmoidf_(az[i] + bz);
      float hn = anhh[i] + anhl[i]*(1.0f/2048.0f) + bn;
      float nn = tanhf_(anxh[i] + anxl[i]*(1.0f/2048.0f) + bin + rr*hn);
      union { unsigned short u; f16 h; } cr; cr.u = hprev[i];
      float hv = nn + zz*((float)cr.h - nn);
      union { f16 h; unsigned short u; } cw; cw.h = (f16)hv;
      hprev[i] = cw.u;
      hstage[(wv*16 + quad*4 + i)*24 + nlane] = cw.h;   // LDS transpose stage
    }
    __syncthreads();                             // B3: stage complete
    f16x8 v8 = {};
    f16* pc = nullptr;
    if (tid < 128) {                             // coalesced 16B h stores
      const int row = tid >> 1, half = tid & 1;
      v8 = *(const f16x8*)(hstage + row*24 + half*8);
      const size_t col = (size_t)(bh*64 + row)*HID + g*16 + half*8;
      pc = hcrs + (size_t)(l*CRS_D + (t & (CRS_D-1)))*BATCH*HID + col;
      if (FAST) st16_l2(hloc + (size_t)(l*LOC_D + (t & 1))*BATCH*HID + col, v8);
      else      st16_sc1(pc, v8);
    }
    asm volatile("s_waitcnt vmcnt(0)" ::: "memory");
    __syncthreads();                             // B4: h(t) drained (locally in FAST)
    if (tid == 0) { if (FAST) st4_l2(FL + g, t + 1); else st4_sc1(FL + g, t + 1); }
    if (FAST && tid < 128) st16_sc1(pc, v8);     // deferred cross copy; drained by next step's vmcnt(0)
    if (tid == 0) st4_sc1(FC + gid*32 + g, t);   // cross publish: finished t, h(t-1) remotely visible
  }
  // final drain + publish so consumers of h(1023) aren't starved by the deferral
  asm volatile("s_waitcnt vmcnt(0)" ::: "memory");
  if (tid == 0) st4_sc1((int*)(ws + OFF_FCROSS) + gid*32 + g, T_STEPS);
}

__device__ __forceinline__ void proj_loop(const int p, const float* __restrict__ b_out,
    float* __restrict__ out, char* __restrict__ ws, const f16* wolds, int* s_bail)
{
  const int tid = threadIdx.x;
  const int lane = tid & 63, wv = tid >> 6;
  const int quad = lane >> 4, ko = quad*8, nlane = lane & 15;
  const int bt = p / 5, vt = p % 5, half = bt >> 1;
  (void)vt;
  int* FC = (int*)(ws + OFF_FCROSS);
  int* FP = (int*)(ws + OFF_FPROJ);
  f16* hcrs = (f16*)(ws + OFF_CROSS);
  const int v = vt*16 + nlane;
  const float bo = (v < VOC) ? b_out[v] : 0.0f;
  for (int t = 0; t < T_STEPS; ++t) {
    if (wv == 0) {                               // need h_2(t): FC >= t+1
      const int m = lane & 31;
      const int cap = *s_bail ? (1<<8) : (1<<22);
      int spins = 0;
      while (1) {
        int vv = 0x7FFFFFFF;
        if (lane < 32) vv = ld4_sc(FC + (4 + half)*32 + m);
        if (__all(vv >= t + 1)) break;
        if (++spins > cap) { *s_bail = 1; break; }
        __builtin_amdgcn_s_sleep(1);
      }
    }
    __syncthreads();
    if (wv < 2) {
      const int bmb = bt*32 + wv*16;
      const f16* hrow = hcrs + ((size_t)(2*CRS_D + (t & (CRS_D-1)))*BATCH + bmb + nlane)*HID + ko;
      f16x8 af[16];
#pragma unroll
      for (int kc = 0; kc < 16; ++kc) af[kc] = ld16_sc(hrow + kc*32);
      asm volatile("s_waitcnt vmcnt(0)" ::: "memory");
#pragma unroll
      for (int kc = 0; kc < 16; ++kc) asm volatile("" : "+v"(af[kc]));
      f32x4 acc{0,0,0,0};
#pragma unroll
      for (int kc = 0; kc < 16; ++kc) {
        f16x8 w = *(const f16x8*)(wolds + ((kc*64 + lane) << 3));
        acc = __builtin_amdgcn_mfma_f32_16x16x32_f16(af[kc], w, acc, 0, 0, 0);
      }
      if (v < VOC) {
#pragma unroll
        for (int i = 0; i < 4; ++i) {
          int bidx = bmb + quad*4 + i;
          out[((size_t)bidx*T_STEPS + t)*VOC + v] = acc[i] + bo;
        }
      }
    }
    __syncthreads();
    if (tid == 0) st4_sc1(FP + p, t);            // finished step t
  }
}

// 256 WGs x 256 threads. Role by XCD (blockIdx%8, round-robin dispatch expected but VERIFIED):
// xcd 0..5 -> (layer = xcd>>1, bh = xcd&1), member g = blockIdx/8 (32 = one full XCD).
// xcd 6 -> projection (20 of 32). xcd 7 + spares -> exit.
// FAST requires: 32 equal XCC ids + cross-group distinctness (bogus-register guard) + a live sc0
// ping-pong visibility test + unanimous vote through the coherence point. Any failure -> SLOW.
__global__ void __launch_bounds__(256) rnn_kernel(const int* __restrict__ xseq,
                           const float* __restrict__ bias, const float* __restrict__ bias_n,
                           const float* __restrict__ b_out, float* __restrict__ out,
                           char* __restrict__ ws) {
  __shared__ __align__(16) f16 wlds[65536];           // 131,072 B
  __shared__ __align__(16) f16 wolds[8192];           // 16,384 B
  __shared__ __align__(16) f16 hstage[64*24];         // 3,072 B
  __shared__ int s_fast;
  __shared__ int s_bail;
  const int xcd = blockIdx.x & 7, idx = blockIdx.x >> 3;
  const int tid = threadIdx.x;
  if (xcd < 6) {
    const int l = xcd >> 1, bh = xcd & 1, g = idx, gid = xcd;
    {
      const f16x8* src = (const f16x8*)((const f16*)(ws + OFF_WPACK) + ((size_t)(l*32+g) << 16));
      f16x8* dst = (f16x8*)wlds;
      for (int i = tid; i < 8192; i += 256) dst[i] = src[i];
    }
    if (tid == 0) {
      int* X  = (int*)(ws + OFF_XCCS);
      int* R  = (int*)(ws + OFF_RCNT);
      int* TS = (int*)(ws + OFF_TEST) + gid*32;
      int* VT = (int*)(ws + OFF_VOTE) + gid*32;
      int xcc = 0;
      asm volatile("s_getreg_b32 %0, hwreg(HW_REG_XCC_ID)" : "=s"(xcc));
      st4_sc1(X + gid*32 + g, xcc);
      asm volatile("s_waitcnt vmcnt(0)" ::: "memory");
      __hip_atomic_fetch_add(R + gid, 1, __ATOMIC_RELAXED, __HIP_MEMORY_SCOPE_AGENT);
      int ok = 1;
      {                                     // global rendezvous: all 6 groups reported
        int spins = 0;
        while (1) {
          int done = 1;
          for (int q = 0; q < 6; ++q)
            if (__hip_atomic_load(R + q, __ATOMIC_RELAXED, __HIP_MEMORY_SCOPE_AGENT) < 32) { done = 0; break; }
          if (done) break;
          if (++spins > (1<<20)) { ok = 0; break; }
          __builtin_amdgcn_s_sleep(8);
        }
      }
      if (ok) {
        const int first = ld4_sc(X + gid*32);
        for (int m = 1; m < 32; ++m) if (ld4_sc(X + gid*32 + m) != first) { ok = 0; break; }
        if (ok) {                           // bogus-register guard: 6 groups can't share one XCD
          int allsame = 1;
          for (int q = 0; q < 6; ++q) if (ld4_sc(X + q*32) != first) { allsame = 0; break; }
          if (allsame) ok = 0;
        }
      }
      if (ok) {                             // live sc0 visibility test within the (claimed) XCD
        st4_l2(TS + g, 1000 + g);
        int spins = 0;
        while (1) {
          int good = 1;
          for (int m = 0; m < 32; ++m) if (ld4_l2(TS + m) != 1000 + m) { good = 0; break; }
          if (good) break;
          if (++spins > (1<<16)) { ok = 0; break; }
          __builtin_amdgcn_s_sleep(2);
        }
      }
      st4_sc1(VT + g, 1 + ok);
      asm volatile("s_waitcnt vmcnt(0)" ::: "memory");
      int fast = 1;
      {                                     // unanimous vote gather
        int spins = 0;
        while (1) {
          int seen = 1, allf = 1;
          for (int m = 0; m < 32; ++m) {
            int vv = ld4_sc(VT + m);
            if (vv == 0) { seen = 0; break; }
            if (vv != 2) allf = 0;
          }
          if (seen) { fast = allf; break; }
          if (++spins > (1<<20)) { fast = 0; break; }
          __builtin_amdgcn_s_sleep(2);
        }
      }
      s_fast = fast;
      s_bail = 0;
    }
    __syncthreads();                                  // also covers wlds staging
    if (s_fast) layer_loop<true >(l, bh, g, xseq, bias, bias_n, ws, wlds, hstage, &s_bail);
    else        layer_loop<false>(l, bh, g, xseq, bias, bias_n, ws, wlds, hstage, &s_bail);
  } else if (xcd == 6 && idx < 20) {
    const int p = idx, vt = p % 5;
    {
      const f16x8* src = (const f16x8*)((const f16*)(ws + OFF_WOUT) + vt*8192);
      f16x8* dst = (f16x8*)wolds;
      for (int i = tid; i < 1024; i += 256) dst[i] = src[i];
    }
    if (tid == 0) s_bail = 0;
    __syncthreads();
    proj_loop(p, b_out, (float*)out, ws, wolds, &s_bail);
  }
}

extern "C" void kernel_launch(void* const* d_in, const int* in_sizes, int n_in,
                              void* d_out, int out_size, void* d_ws, size_t ws_size,
                              hipStream_t stream) {
  const int*   xseq  = (const int*)d_in[0];
  const float* emb   = (const float*)d_in[1];
  const float* w_ih  = (const float*)d_in[2];
  const float* w_hh  = (const float*)d_in[3];
  const float* b     = (const float*)d_in[4];
  const float* b_n   = (const float*)d_in[5];
  const float* w_out = (const float*)d_in[6];
  const float* b_out = (const float*)d_in[7];
  char* ws = (char*)d_ws;

  // zero flags + both h rings (h[-1] = 0 initial state); re-done every call
  (void)hipMemsetAsync(d_ws, 0, OFF_WPACK, stream);
  hipLaunchKernelGGL(convert_kernel, dim3(4096), dim3(256), 0, stream,
                     emb, w_ih, w_hh, w_out, ws);
  hipLaunchKernelGGL(rnn_kernel, dim3(256), dim3(256), 0, stream,
                     xseq, b, b_n, b_out, (float*)d_out, ws);
}

// Round 4
// 10486.939 us; speedup vs baseline: 15.8103x; 15.8103x over previous
//
#include <hip/hip_runtime.h>

typedef _Float16 f16;
typedef _Float16 f16x8 __attribute__((ext_vector_type(8)));
typedef float f32x4 __attribute__((ext_vector_type(4)));

#define T_STEPS 1024
#define BATCH 128
#define HID 512
#define VOC 65
#define DRING 8
#define NLWG 192              // 3 layers * 32 dim-slices * 2 batch-halves
#define NPWG 20               // 4 b-tiles * 5 v-tiles
#define CPAD 16               // ints per counter (64B line)

// workspace layout (bytes) — identical footprint to the proven round-0 kernel
// counters: CNT[i*CPAD], i=0..5 layer groups (gid=l*2+bh), i=6..7 proj halves.
// CNT[gid]   = sum over member WGs of (steps completed)  -> 32*(t+1) when group finished step t
// CNT[6+bh]  = sum over 10 proj WGs of (steps completed) -> 10*(t+1) when proj half finished step t
#define OFF_CNT 0
#define OFF_HRING 32768
#define HRING_BYTES (3*DRING*BATCH*HID*2)            // 3,145,728
#define OFF_WPACK (OFF_HRING + HRING_BYTES)          // 3,178,496
#define WPACK_BYTES (3*32*65536*2)                   // 12,582,912
#define OFF_WOUT (OFF_WPACK + WPACK_BYTES)           // 15,761,408
#define WOUT_BYTES (5*16*512*2)                      // 81,920
#define OFF_EMB (OFF_WOUT + WOUT_BYTES)              // 15,843,328

__device__ __forceinline__ float sigmoidf_(float x){ return 1.0f/(1.0f+__expf(-x)); }
__device__ __forceinline__ float tanhf_(float x){ return 1.0f - 2.0f/(__expf(2.0f*x)+1.0f); }

// coherent 16B load: bypass L1+L2, read from coherence point (fresh cross-XCD data)
__device__ __forceinline__ f16x8 ld16_sc(const f16* p) {
  f16x8 r;
  asm volatile("global_load_dwordx4 %0, %1, off sc0 sc1" : "=v"(r) : "v"(p) : "memory");
  return r;
}
__device__ __forceinline__ void st16_sc1(f16* p, f16x8 v){
  asm volatile("global_store_dwordx4 %0, %1, off sc1"::"v"(p),"v"(v):"memory"); }

// Pack weights FRAG-MAJOR: per (layer l, slice g): 4 gate-tiles (r, z, n-hi, n-lo*2048)
// x 32 kc x [64 lanes x 8 f16] so a wave's ds_read_b128 is conflict-free.
__global__ void convert_kernel(const float* __restrict__ emb, const float* __restrict__ w_ih,
                               const float* __restrict__ w_hh, const float* __restrict__ w_out,
                               char* __restrict__ ws) {
  f16* wpack = (f16*)(ws + OFF_WPACK);
  f16* wout  = (f16*)(ws + OFF_WOUT);
  f16* embh  = (f16*)(ws + OFF_EMB);
  const int NW = 3*32*65536;
  const int TOT = NW + 40960 + VOC*HID;
  for (int e = blockIdx.x*blockDim.x + threadIdx.x; e < TOT; e += gridDim.x*blockDim.x) {
    if (e < NW) {
      int l = e >> 21, rem = e & 0x1FFFFF;
      int g = rem >> 16, idx = rem & 0xFFFF;
      int gt = idx >> 14, kc = (idx >> 9) & 31, lane = (idx >> 3) & 63, jj = idx & 7;
      int n = lane & 15, q = lane >> 4;
      int k = kc*32 + q*8 + jj, d = g*16 + n;
      int row = (gt==0) ? d : (gt==1) ? 512+d : 1024+d;
      float f = (k < 512) ? w_ih[((size_t)(l*1536+row)<<9) + k]
                          : w_hh[((size_t)(l*1536+row)<<9) + (k-512)];
      f16 h;
      if (gt < 3) h = (f16)f;
      else { f16 hi = (f16)f; h = (f16)((f - (float)hi)*2048.0f); }
      wpack[e] = h;
    } else if (e < NW + 40960) {
      int idx = e - NW;
      int vt = idx >> 13, r2 = idx & 8191;
      int kc = r2 >> 9, lane = (r2 >> 3) & 63, jj = r2 & 7;
      int n = lane & 15, q = lane >> 4;
      int v = vt*16 + n, k = kc*32 + q*8 + jj;
      wout[idx] = (v < VOC) ? (f16)w_out[((size_t)v<<9) + k] : (f16)0.0f;
    } else {
      int idx = e - NW - 40960;
      embh[idx] = (f16)emb[idx];
    }
  }
}

// Persistent kernel, 212 WGs x 256 threads — round-0 protocol with ONE aggregated
// cumulative counter per group instead of 32 per-WG flags:
//  * poll = single 64B-line load (32x less coherence-point traffic than round 0)
//  * producers: vmcnt(0) drain, then one device-scope atomicAdd(+1) per WG per step
//  * dependency targets identical to round 0, in cumulative form
__global__ void __launch_bounds__(256) rnn_kernel(const int* __restrict__ xseq,
                           const float* __restrict__ bias, const float* __restrict__ bias_n,
                           const float* __restrict__ b_out, float* __restrict__ out,
                           char* __restrict__ ws) {
  int* CNT = (int*)(ws + OFF_CNT);
  f16* hring = (f16*)(ws + OFF_HRING);                // [3][8][128][512]
  const int wg = blockIdx.x;
  const int tid = threadIdx.x;
  const int lane = tid & 63, wv = tid >> 6;
  const int quad = lane >> 4, ko = quad*8, nlane = lane & 15;

  __shared__ __align__(16) f16 wlds[65536];           // 131,072 B
  __shared__ __align__(16) f16 wolds[8192];           // 16,384 B
  __shared__ __align__(16) f16 hstage[64*24];         // 3,072 B (stride 24 f16 = 48B rows)
  __shared__ int s_bail;

  if (wg < NLWG) {
    const int l = wg / 64, r = wg % 64, g = r >> 1, bh = r & 1;
    const int gid = l*2 + bh;
    {
      const f16x8* src = (const f16x8*)((const f16*)(ws + OFF_WPACK) + ((size_t)(l*32+g) << 16));
      f16x8* dst = (f16x8*)wlds;
      for (int i = tid; i < 8192; i += 256) dst[i] = src[i];
    }
    const int j = g*16 + nlane;
    const float br  = bias[l*1536 + j];
    const float bz  = bias[l*1536 + 512 + j];
    const float bin = bias[l*1536 + 1024 + j];
    const float bn  = bias_n[l*512 + j];
    const int bm = bh*64 + wv*16 + nlane;             // A-operand batch row

    // single-line poll assignments:
    //  wv0: lanes<32 -> self CNT >= 32*t ; lanes>=32 -> upstream CNT >= 32*(t+1) (l>0)
    //  wv1: back-pressure: downstream CNT >= K*(t-7)  (K=32 layer / 10 proj), only for t>=8
    const int* p0 = CNT + gid*CPAD;                   // self
    const int* p0b = (l > 0) ? (CNT + (gid-2)*CPAD) : p0;  // upstream (or self dup for l==0)
    const int* p1 = (l < 2) ? (CNT + (gid+2)*CPAD) : (CNT + (6+bh)*CPAD);
    const int dsK = (l < 2) ? 32 : 10;

    if (tid == 0) s_bail = 0;
    __syncthreads();
    // register-resident B-frags for r and z gates; conflict-free reads
    f16x8 wr[32], wz[32];
#pragma unroll
    for (int kc = 0; kc < 32; ++kc) {
      wr[kc] = *(const f16x8*)(wlds + (((0*32 + kc)*64 + lane) << 3));
      wz[kc] = *(const f16x8*)(wlds + (((1*32 + kc)*64 + lane) << 3));
    }
    const f16* embh = (const f16*)(ws + OFF_EMB);
    unsigned short hprev[4] = {0, 0, 0, 0};           // h(t-1) for this thread's (row,col), f16 bits

    for (int t = 0; t < T_STEPS; ++t) {
      if (wv == 0) {
        const int* pp  = (lane < 32) ? p0 : p0b;
        const int  tgt = (lane < 32) ? 32*t : ((l > 0) ? 32*(t+1) : 32*t);
        const int cap = s_bail ? (1<<8) : (1<<22);
        int spins = 0;
        while (1) {
          int v = __hip_atomic_load(pp, __ATOMIC_RELAXED, __HIP_MEMORY_SCOPE_AGENT);
          if (__all(v >= tgt)) break;
          if (++spins > cap) { s_bail = 1; break; }   // hang-safety: fail visibly, not forever
          __builtin_amdgcn_s_sleep(1);
        }
      } else if (wv == 1 && t >= DRING) {
        const int tgt = dsK*(t - (DRING-1));
        const int cap = s_bail ? (1<<8) : (1<<22);
        int spins = 0;
        while (1) {
          int v = __hip_atomic_load(p1, __ATOMIC_RELAXED, __HIP_MEMORY_SCOPE_AGENT);
          if (__all(v >= tgt)) break;
          if (++spins > cap) { s_bail = 1; break; }
          __builtin_amdgcn_s_sleep(1);
        }
      }
      __syncthreads();

      const int slot_w = t & (DRING-1), slot_r = (t + DRING - 1) & (DRING-1);
      f16x8 afr[32];
      if (l == 0) {
        int idx = xseq[bm*T_STEPS + t];
        const f16* xr = embh + (size_t)idx*HID + ko;  // immutable: plain cached loads
#pragma unroll
        for (int kc = 0; kc < 16; ++kc) afr[kc] = *(const f16x8*)(xr + kc*32);
      } else {
        const f16* xr = hring + ((size_t)((l-1)*DRING + slot_w)*BATCH + bm)*HID + ko;
#pragma unroll
        for (int kc = 0; kc < 16; ++kc) afr[kc] = ld16_sc(xr + kc*32);
      }
      {
        const f16* hrk = hring + ((size_t)(l*DRING + slot_r)*BATCH + bm)*HID + ko;
#pragma unroll
        for (int kc = 0; kc < 16; ++kc) afr[16 + kc] = ld16_sc(hrk + kc*32);
      }
      asm volatile("s_waitcnt vmcnt(0)" ::: "memory");
#pragma unroll
      for (int kc = 0; kc < 32; ++kc) asm volatile("" : "+v"(afr[kc]));

      f32x4 ar{0,0,0,0}, az{0,0,0,0}, anxh{0,0,0,0}, anxl{0,0,0,0}, anhh{0,0,0,0}, anhl{0,0,0,0};
#pragma unroll
      for (int kc = 0; kc < 32; ++kc) {
        f16x8 wnh = *(const f16x8*)(wlds + (((2*32 + kc)*64 + lane) << 3));
        f16x8 wnl = *(const f16x8*)(wlds + (((3*32 + kc)*64 + lane) << 3));
        ar = __builtin_amdgcn_mfma_f32_16x16x32_f16(afr[kc], wr[kc], ar, 0, 0, 0);
        az = __builtin_amdgcn_mfma_f32_16x16x32_f16(afr[kc], wz[kc], az, 0, 0, 0);
        if (kc < 16) {
          anxh = __builtin_amdgcn_mfma_f32_16x16x32_f16(afr[kc], wnh, anxh, 0, 0, 0);
          anxl = __builtin_amdgcn_mfma_f32_16x16x32_f16(afr[kc], wnl, anxl, 0, 0, 0);
        } else {
          anhh = __builtin_amdgcn_mfma_f32_16x16x32_f16(afr[kc], wnh, anhh, 0, 0, 0);
          anhl = __builtin_amdgcn_mfma_f32_16x16x32_f16(afr[kc], wnl, anhl, 0, 0, 0);
        }
      }
      // epilogue: D layout col(lane&15)=dim j, row_local(wv*16+quad*4+i)=batch (within bh half)
#pragma unroll
      for (int i = 0; i < 4; ++i) {
        float rr = sigmoidf_(ar[i] + br);
        float zz = sigmoidf_(az[i] + bz);
        float hn = anhh[i] + anhl[i]*(1.0f/2048.0f) + bn;
        float nn = tanhf_(anxh[i] + anxl[i]*(1.0f/2048.0f) + bin + rr*hn);
        union { unsigned short u; f16 h; } cr; cr.u = hprev[i];
        float hv = nn + zz*((float)cr.h - nn);
        union { f16 h; unsigned short u; } cw; cw.h = (f16)hv;
        hprev[i] = cw.u;
        hstage[(wv*16 + quad*4 + i)*24 + nlane] = cw.h;   // LDS transpose stage
      }
      __syncthreads();
      // coalesced 16B h stores: 128 threads, one 16B chunk each (row, 8 cols)
      if (tid < 128) {
        int row = tid >> 1, half = tid & 1;
        f16x8 v8 = *(const f16x8*)(hstage + row*24 + half*8);
        f16* hw = hring + ((size_t)(l*DRING + slot_w)*BATCH + bh*64 + row)*HID + g*16 + half*8;
        st16_sc1(hw, v8);
      }
      asm volatile("s_waitcnt vmcnt(0)" ::: "memory"); // sc1 stores reached coherence point
      __syncthreads();
      if (tid == 0)
        __hip_atomic_fetch_add(CNT + gid*CPAD, 1,
                               __ATOMIC_RELAXED, __HIP_MEMORY_SCOPE_AGENT);
    }
  } else if (wg < NLWG + NPWG) {
    const int p = wg - NLWG, bt = p / 5, vt = p % 5, half = bt >> 1;
    {
      const f16x8* src = (const f16x8*)((const f16*)(ws + OFF_WOUT) + vt*8192);
      f16x8* dst = (f16x8*)wolds;
      for (int i = tid; i < 1024; i += 256) dst[i] = src[i];
    }
    const int v = vt*16 + nlane;
    const float bo = (v < VOC) ? b_out[v] : 0.0f;
    if (tid == 0) s_bail = 0;
    __syncthreads();
    const int* ph = CNT + (4 + half)*CPAD;            // layer-2 group for this batch half
    for (int t = 0; t < T_STEPS; ++t) {
      if (wv == 0) {
        const int tgt = 32*(t + 1);
        const int cap = s_bail ? (1<<8) : (1<<22);
        int spins = 0;
        while (1) {
          int vv = __hip_atomic_load(ph, __ATOMIC_RELAXED, __HIP_MEMORY_SCOPE_AGENT);
          if (__all(vv >= tgt)) break;
          if (++spins > cap) { s_bail = 1; break; }
          __builtin_amdgcn_s_sleep(1);
        }
      }
      __syncthreads();
      if (wv < 2) {
        const int bmb = bt*32 + wv*16;
        const f16* hrow = hring + ((size_t)(2*DRING + (t & (DRING-1)))*BATCH + bmb + nlane)*HID + ko;
        f16x8 af[16];
#pragma unroll
        for (int kc = 0; kc < 16; ++kc) af[kc] = ld16_sc(hrow + kc*32);
        asm volatile("s_waitcnt vmcnt(0)" ::: "memory");
#pragma unroll
        for (int kc = 0; kc < 16; ++kc) asm volatile("" : "+v"(af[kc]));
        f32x4 acc{0,0,0,0};
#pragma unroll
        for (int kc = 0; kc < 16; ++kc) {
          f16x8 w = *(const f16x8*)(wolds + ((kc*64 + lane) << 3));
          acc = __builtin_amdgcn_mfma_f32_16x16x32_f16(af[kc], w, acc, 0, 0, 0);
        }
        if (v < VOC) {
#pragma unroll
          for (int i = 0; i < 4; ++i) {
            int bidx = bmb + quad*4 + i;
            out[((size_t)bidx*T_STEPS + t)*VOC + v] = acc[i] + bo;
          }
        }
      }
      __syncthreads();
      if (tid == 0)
        __hip_atomic_fetch_add(CNT + (6 + half)*CPAD, 1,
                               __ATOMIC_RELAXED, __HIP_MEMORY_SCOPE_AGENT);
    }
  }
}

extern "C" void kernel_launch(void* const* d_in, const int* in_sizes, int n_in,
                              void* d_out, int out_size, void* d_ws, size_t ws_size,
                              hipStream_t stream) {
  const int*   xseq  = (const int*)d_in[0];
  const float* emb   = (const float*)d_in[1];
  const float* w_ih  = (const float*)d_in[2];
  const float* w_hh  = (const float*)d_in[3];
  const float* b     = (const float*)d_in[4];
  const float* b_n   = (const float*)d_in[5];
  const float* w_out = (const float*)d_in[6];
  const float* b_out = (const float*)d_in[7];
  char* ws = (char*)d_ws;

  // zero counters + h ring (h[-1] = 0 initial state); re-done every call
  (void)hipMemsetAsync(d_ws, 0, OFF_HRING + HRING_BYTES, stream);
  hipLaunchKernelGGL(convert_kernel, dim3(4096), dim3(256), 0, stream,
                     emb, w_ih, w_hh, w_out, ws);
  hipLaunchKernelGGL(rnn_kernel, dim3(NLWG + NPWG), dim3(256), 0, stream,
                     xseq, b, b_n, b_out, (float*)d_out, ws);
}

// Round 5
// 7494.361 us; speedup vs baseline: 22.1235x; 1.3993x over previous
//
#include <hip/hip_runtime.h>

typedef _Float16 f16;
typedef _Float16 f16x8 __attribute__((ext_vector_type(8)));
typedef float f32x4 __attribute__((ext_vector_type(4)));

#define T_STEPS 1024
#define BATCH 128
#define HID 512
#define VOC 65
#define DRING 8
#define NLWG 192              // 3 layers * 32 dim-slices * 2 batch-halves
#define NPWG 20               // 4 b-tiles * 5 v-tiles
#define FPAD 16               // ints per flag (64B line) — kills flag-line contention

// workspace layout (bytes) — identical to the proven round-0 kernel
#define OFF_READY 0           // padded flags: [(l*64+bh*32+g)*FPAD], proj at [(192+p)*FPAD]
#define OFF_HRING 32768
#define HRING_BYTES (3*DRING*BATCH*HID*2)            // 3,145,728
#define OFF_WPACK (OFF_HRING + HRING_BYTES)          // 3,178,496
#define WPACK_BYTES (3*32*65536*2)                   // 12,582,912
#define OFF_WOUT (OFF_WPACK + WPACK_BYTES)           // 15,761,408
#define WOUT_BYTES (5*16*512*2)                      // 81,920
#define OFF_EMB (OFF_WOUT + WOUT_BYTES)              // 15,843,328

// h-ring layout (TRANSPOSED vs round 0): [l][slot][bh][d8(64)][row(64)][8 f16]
// One (l,slot,bh) half = 32768 f16 = 64KB. A wave's ld16_sc now reads 4x256B
// contiguous chunks (16 fully-used 64B lines) instead of 64 quarter-used lines.
#define HHALF 32768           // f16 elements per (l,slot,bh)

__device__ __forceinline__ float sigmoidf_(float x){ return 1.0f/(1.0f+__expf(-x)); }
__device__ __forceinline__ float tanhf_(float x){ return 1.0f - 2.0f/(__expf(2.0f*x)+1.0f); }

// coherent 16B load: bypass L1+L2, read from coherence point (fresh cross-XCD data)
__device__ __forceinline__ f16x8 ld16_sc(const f16* p) {
  f16x8 r;
  asm volatile("global_load_dwordx4 %0, %1, off sc0 sc1" : "=v"(r) : "v"(p) : "memory");
  return r;
}
__device__ __forceinline__ void st16_sc1(f16* p, f16x8 v){
  asm volatile("global_store_dwordx4 %0, %1, off sc1"::"v"(p),"v"(v):"memory"); }

// Pack weights FRAG-MAJOR: per (layer l, slice g): 4 gate-tiles (r, z, n-hi, n-lo*2048)
// x 32 kc x [64 lanes x 8 f16] so a wave's ds_read_b128 is conflict-free.
__global__ void convert_kernel(const float* __restrict__ emb, const float* __restrict__ w_ih,
                               const float* __restrict__ w_hh, const float* __restrict__ w_out,
                               char* __restrict__ ws) {
  f16* wpack = (f16*)(ws + OFF_WPACK);
  f16* wout  = (f16*)(ws + OFF_WOUT);
  f16* embh  = (f16*)(ws + OFF_EMB);
  const int NW = 3*32*65536;
  const int TOT = NW + 40960 + VOC*HID;
  for (int e = blockIdx.x*blockDim.x + threadIdx.x; e < TOT; e += gridDim.x*blockDim.x) {
    if (e < NW) {
      int l = e >> 21, rem = e & 0x1FFFFF;
      int g = rem >> 16, idx = rem & 0xFFFF;
      int gt = idx >> 14, kc = (idx >> 9) & 31, lane = (idx >> 3) & 63, jj = idx & 7;
      int n = lane & 15, q = lane >> 4;
      int k = kc*32 + q*8 + jj, d = g*16 + n;
      int row = (gt==0) ? d : (gt==1) ? 512+d : 1024+d;
      float f = (k < 512) ? w_ih[((size_t)(l*1536+row)<<9) + k]
                          : w_hh[((size_t)(l*1536+row)<<9) + (k-512)];
      f16 h;
      if (gt < 3) h = (f16)f;
      else { f16 hi = (f16)f; h = (f16)((f - (float)hi)*2048.0f); }
      wpack[e] = h;
    } else if (e < NW + 40960) {
      int idx = e - NW;
      int vt = idx >> 13, r2 = idx & 8191;
      int kc = r2 >> 9, lane = (r2 >> 3) & 63, jj = r2 & 7;
      int n = lane & 15, q = lane >> 4;
      int v = vt*16 + n, k = kc*32 + q*8 + jj;
      wout[idx] = (v < VOC) ? (f16)w_out[((size_t)v<<9) + k] : (f16)0.0f;
    } else {
      int idx = e - NW - 40960;
      embh[idx] = (f16)emb[idx];
    }
  }
}

// Persistent kernel, 212 WGs x 256 threads — round-0 protocol (proven 8752us) with the
// h-ring TRANSPOSED for line-dense coherence-point traffic:
//  * loads: 4x256B contiguous chunks per instruction (16 full lines, was 64 quarter-lines)
//  * stores: two 1KB contiguous chunks per WG (full lines, was 64 partial lines)
//  * flags/polls byte-identical to round 0 (round 4 proved atomic aggregation regresses)
__global__ void __launch_bounds__(256) rnn_kernel(const int* __restrict__ xseq,
                           const float* __restrict__ bias, const float* __restrict__ bias_n,
                           const float* __restrict__ b_out, float* __restrict__ out,
                           char* __restrict__ ws) {
  int* F = (int*)(ws + OFF_READY);
  f16* hring = (f16*)(ws + OFF_HRING);                // [3][8][2][64][64][8] transposed
  const int wg = blockIdx.x;
  const int tid = threadIdx.x;
  const int lane = tid & 63, wv = tid >> 6;
  const int quad = lane >> 4, nlane = lane & 15;

  __shared__ __align__(16) f16 wlds[65536];           // 131,072 B
  __shared__ __align__(16) f16 wolds[8192];           // 16,384 B
  __shared__ __align__(16) f16 hstage[64*24];         // 3,072 B (stride 24 f16 = 48B rows)

  if (wg < NLWG) {
    const int l = wg / 64, r = wg % 64, g = r >> 1, bh = r & 1;
    {
      const f16x8* src = (const f16x8*)((const f16*)(ws + OFF_WPACK) + ((size_t)(l*32+g) << 16));
      f16x8* dst = (f16x8*)wlds;
      for (int i = tid; i < 8192; i += 256) dst[i] = src[i];
    }
    const int j = g*16 + nlane;
    const float br  = bias[l*1536 + j];
    const float bz  = bias[l*1536 + 512 + j];
    const float bin = bias[l*1536 + 1024 + j];
    const float bn  = bias_n[l*512 + j];
    const int bm = bh*64 + wv*16 + nlane;             // A-operand batch row (for l==0 x gather)
    // per-lane offset into a transposed (l,slot,bh) half: [d8=kc*4+quad][row=wv*16+nlane][8]
    const int tofs = quad*512 + (wv*16 + nlane)*8;    // + kc*2048 per kc

    // per-lane poll assignment: wave0 = self(>=t, lanes 0-31) + prev(>=t+1, lanes 32-63);
    // wave1 = downstream back-pressure (>=t-7)
    const int* pollp = F; int padd = 0; int pact = 0;
    if (wv == 0) {
      if (lane < 32)      { pollp = F + (l*64 + bh*32 + lane)*FPAD;          padd = 0;  pact = 1; }
      else if (l > 0)     { pollp = F + ((l-1)*64 + bh*32 + (lane-32))*FPAD; padd = 1;  pact = 1; }
    } else if (wv == 1) {
      if (l < 2) { if (lane < 32) { pollp = F + ((l+1)*64 + bh*32 + lane)*FPAD; padd = -(DRING-1); pact = 1; } }
      else       { if (lane < 10) { pollp = F + (192 + bh*10 + lane)*FPAD;      padd = -(DRING-1); pact = 1; } }
    }
    __syncthreads();
    // register-resident B-frags for r and z gates; conflict-free reads
    f16x8 wr[32], wz[32];
#pragma unroll
    for (int kc = 0; kc < 32; ++kc) {
      wr[kc] = *(const f16x8*)(wlds + (((0*32 + kc)*64 + lane) << 3));
      wz[kc] = *(const f16x8*)(wlds + (((1*32 + kc)*64 + lane) << 3));
    }
    const f16* embh = (const f16*)(ws + OFF_EMB);
    unsigned short hprev[4] = {0, 0, 0, 0};           // h(t-1) for this thread's (row, col) — f16 bits

    for (int t = 0; t < T_STEPS; ++t) {
      if (wv < 2) {
        const int tgt = t + padd;
        int spins = 0;
        while (1) {
          int v = 0x7FFFFFFF;
          if (pact) v = __hip_atomic_load(pollp, __ATOMIC_RELAXED, __HIP_MEMORY_SCOPE_AGENT);
          if (__all(v >= tgt)) break;
          if (++spins > (1 << 22)) break;             // hang-safety: fail visibly, not forever
          __builtin_amdgcn_s_sleep(1);
        }
      }
      __syncthreads();

      const int slot_w = t & (DRING-1), slot_r = (t + DRING - 1) & (DRING-1);
      f16x8 afr[32];
      if (l == 0) {
        int idx = xseq[bm*T_STEPS + t];
        const f16* xr = embh + (size_t)idx*HID + quad*8;   // immutable: plain cached loads
#pragma unroll
        for (int kc = 0; kc < 16; ++kc) afr[kc] = *(const f16x8*)(xr + kc*32);
      } else {
        const f16* xr = hring + (size_t)(((l-1)*DRING + slot_w)*2 + bh)*HHALF + tofs;
#pragma unroll
        for (int kc = 0; kc < 16; ++kc) afr[kc] = ld16_sc(xr + kc*2048);
      }
      {
        const f16* hrk = hring + (size_t)((l*DRING + slot_r)*2 + bh)*HHALF + tofs;
#pragma unroll
        for (int kc = 0; kc < 16; ++kc) afr[16 + kc] = ld16_sc(hrk + kc*2048);
      }
      asm volatile("s_waitcnt vmcnt(0)" ::: "memory");
#pragma unroll
      for (int kc = 0; kc < 32; ++kc) asm volatile("" : "+v"(afr[kc]));

      f32x4 ar{0,0,0,0}, az{0,0,0,0}, anxh{0,0,0,0}, anxl{0,0,0,0}, anhh{0,0,0,0}, anhl{0,0,0,0};
#pragma unroll
      for (int kc = 0; kc < 32; ++kc) {
        f16x8 wnh = *(const f16x8*)(wlds + (((2*32 + kc)*64 + lane) << 3));
        f16x8 wnl = *(const f16x8*)(wlds + (((3*32 + kc)*64 + lane) << 3));
        ar = __builtin_amdgcn_mfma_f32_16x16x32_f16(afr[kc], wr[kc], ar, 0, 0, 0);
        az = __builtin_amdgcn_mfma_f32_16x16x32_f16(afr[kc], wz[kc], az, 0, 0, 0);
        if (kc < 16) {
          anxh = __builtin_amdgcn_mfma_f32_16x16x32_f16(afr[kc], wnh, anxh, 0, 0, 0);
          anxl = __builtin_amdgcn_mfma_f32_16x16x32_f16(afr[kc], wnl, anxl, 0, 0, 0);
        } else {
          anhh = __builtin_amdgcn_mfma_f32_16x16x32_f16(afr[kc], wnh, anhh, 0, 0, 0);
          anhl = __builtin_amdgcn_mfma_f32_16x16x32_f16(afr[kc], wnl, anhl, 0, 0, 0);
        }
      }
      // epilogue: D layout col(lane&15)=dim j, row_local(wv*16+quad*4+i)=batch (within bh half)
#pragma unroll
      for (int i = 0; i < 4; ++i) {
        float rr = sigmoidf_(ar[i] + br);
        float zz = sigmoidf_(az[i] + bz);
        float hn = anhh[i] + anhl[i]*(1.0f/2048.0f) + bn;
        float nn = tanhf_(anxh[i] + anxl[i]*(1.0f/2048.0f) + bin + rr*hn);
        union { unsigned short u; f16 h; } cr; cr.u = hprev[i];
        float hv = nn + zz*((float)cr.h - nn);
        union { f16 h; unsigned short u; } cw; cw.h = (f16)hv;
        hprev[i] = cw.u;
        hstage[(wv*16 + quad*4 + i)*24 + nlane] = cw.h;   // LDS transpose stage
      }
      __syncthreads();
      // h stores, transposed layout: 128 threads -> two 1KB contiguous chunks (full lines)
      if (tid < 128) {
        int d8i = tid >> 6, row = tid & 63;
        f16x8 v8 = *(const f16x8*)(hstage + row*24 + d8i*8);
        f16* hw = hring + (size_t)((l*DRING + slot_w)*2 + bh)*HHALF
                        + (size_t)(2*g + d8i)*512 + row*8;
        st16_sc1(hw, v8);
      }
      asm volatile("s_waitcnt vmcnt(0)" ::: "memory"); // sc1 stores reached coherence point
      __syncthreads();
      if (tid == 0)
        __hip_atomic_store(F + (l*64 + bh*32 + g)*FPAD, t + 1,
                           __ATOMIC_RELAXED, __HIP_MEMORY_SCOPE_AGENT);
    }
  } else if (wg < NLWG + NPWG) {
    const int p = wg - NLWG, bt = p / 5, vt = p % 5, half = bt >> 1;
    {
      const f16x8* src = (const f16x8*)((const f16*)(ws + OFF_WOUT) + vt*8192);
      f16x8* dst = (f16x8*)wolds;
      for (int i = tid; i < 1024; i += 256) dst[i] = src[i];
    }
    const int v = vt*16 + nlane;
    const float bo = (v < VOC) ? b_out[v] : 0.0f;
    __syncthreads();
    for (int t = 0; t < T_STEPS; ++t) {
      if (wv == 0) {
        const int tgt = t + 1;
        int spins = 0;
        while (1) {
          int vv = 0x7FFFFFFF;
          if (lane < 32) vv = __hip_atomic_load(F + (2*64 + half*32 + lane)*FPAD,
                                                __ATOMIC_RELAXED, __HIP_MEMORY_SCOPE_AGENT);
          if (__all(vv >= tgt)) break;
          if (++spins > (1 << 22)) break;
          __builtin_amdgcn_s_sleep(1);
        }
      }
      __syncthreads();
      if (wv < 2) {
        const int row_abs = bt*32 + wv*16 + nlane;     // absolute batch row 0..127
        const int bh2 = row_abs >> 6, rih = row_abs & 63;
        const f16* hrow = hring + (size_t)((2*DRING + (t & (DRING-1)))*2 + bh2)*HHALF
                                + quad*512 + rih*8;
        f16x8 af[16];
#pragma unroll
        for (int kc = 0; kc < 16; ++kc) af[kc] = ld16_sc(hrow + kc*2048);
        asm volatile("s_waitcnt vmcnt(0)" ::: "memory");
#pragma unroll
        for (int kc = 0; kc < 16; ++kc) asm volatile("" : "+v"(af[kc]));
        f32x4 acc{0,0,0,0};
#pragma unroll
        for (int kc = 0; kc < 16; ++kc) {
          f16x8 w = *(const f16x8*)(wolds + ((kc*64 + lane) << 3));
          acc = __builtin_amdgcn_mfma_f32_16x16x32_f16(af[kc], w, acc, 0, 0, 0);
        }
        if (v < VOC) {
          const int bmb = bt*32 + wv*16;
#pragma unroll
          for (int i = 0; i < 4; ++i) {
            int bidx = bmb + quad*4 + i;
            out[((size_t)bidx*T_STEPS + t)*VOC + v] = acc[i] + bo;
          }
        }
      }
      __syncthreads();
      if (tid == 0)
        __hip_atomic_store(F + (192 + p)*FPAD, t + 1, __ATOMIC_RELAXED, __HIP_MEMORY_SCOPE_AGENT);
    }
  }
}

extern "C" void kernel_launch(void* const* d_in, const int* in_sizes, int n_in,
                              void* d_out, int out_size, void* d_ws, size_t ws_size,
                              hipStream_t stream) {
  const int*   xseq  = (const int*)d_in[0];
  const float* emb   = (const float*)d_in[1];
  const float* w_ih  = (const float*)d_in[2];
  const float* w_hh  = (const float*)d_in[3];
  const float* b     = (const float*)d_in[4];
  const float* b_n   = (const float*)d_in[5];
  const float* w_out = (const float*)d_in[6];
  const float* b_out = (const float*)d_in[7];
  char* ws = (char*)d_ws;

  // zero flags + h ring (h[-1] = 0 initial state); re-done every call
  (void)hipMemsetAsync(d_ws, 0, OFF_HRING + HRING_BYTES, stream);
  hipLaunchKernelGGL(convert_kernel, dim3(4096), dim3(256), 0, stream,
                     emb, w_ih, w_hh, w_out, ws);
  hipLaunchKernelGGL(rnn_kernel, dim3(NLWG + NPWG), dim3(256), 0, stream,
                     xseq, b, b_n, b_out, (float*)d_out, ws);
}

// Round 6
// 6919.074 us; speedup vs baseline: 23.9629x; 1.0831x over previous
//
#include <hip/hip_runtime.h>

typedef _Float16 f16;
typedef _Float16 f16x8 __attribute__((ext_vector_type(8)));
typedef float f32x4 __attribute__((ext_vector_type(4)));

#define T_STEPS 1024
#define BATCH 128
#define HID 512
#define VOC 65
#define DRING 8
#define NLWG 192              // 3 layers * 32 dim-slices * 2 batch-halves
#define NPWG 20               // 4 b-tiles * 5 v-tiles
#define FPAD 16               // ints per flag (64B line) — kills flag-line contention

// workspace layout (bytes) — identical to the proven round-0/5 kernel
#define OFF_READY 0           // padded flags: [(l*64+bh*32+g)*FPAD], proj at [(192+p)*FPAD]
#define OFF_HRING 32768
#define HRING_BYTES (3*DRING*BATCH*HID*2)            // 3,145,728
#define OFF_WPACK (OFF_HRING + HRING_BYTES)          // 3,178,496
#define WPACK_BYTES (3*32*65536*2)                   // 12,582,912
#define OFF_WOUT (OFF_WPACK + WPACK_BYTES)           // 15,761,408
#define WOUT_BYTES (5*16*512*2)                      // 81,920
#define OFF_EMB (OFF_WOUT + WOUT_BYTES)              // 15,843,328

// h-ring layout (transposed, proven r5): [l][slot][bh][d8(64)][row(64)][8 f16]
#define HHALF 32768           // f16 elements per (l,slot,bh)

__device__ __forceinline__ float sigmoidf_(float x){ return 1.0f/(1.0f+__expf(-x)); }
__device__ __forceinline__ float tanhf_(float x){ return 1.0f - 2.0f/(__expf(2.0f*x)+1.0f); }

// coherent 16B load: bypass L1+L2, read from coherence point (fresh cross-XCD data)
__device__ __forceinline__ f16x8 ld16_sc(const f16* p) {
  f16x8 r;
  asm volatile("global_load_dwordx4 %0, %1, off sc0 sc1" : "=v"(r) : "v"(p) : "memory");
  return r;
}
// plain cached 16B load (immutable data), asm so issue order/counting is pinned
__device__ __forceinline__ f16x8 ld16_pl(const f16* p) {
  f16x8 r;
  asm volatile("global_load_dwordx4 %0, %1, off" : "=v"(r) : "v"(p) : "memory");
  return r;
}
__device__ __forceinline__ void st16_sc1(f16* p, f16x8 v){
  asm volatile("global_store_dwordx4 %0, %1, off sc1"::"v"(p),"v"(v):"memory"); }

// Pack weights FRAG-MAJOR: per (layer l, slice g): 4 gate-tiles (r, z, n-hi, n-lo*2048)
// x 32 kc x [64 lanes x 8 f16] so a wave's ds_read_b128 is conflict-free.
__global__ void convert_kernel(const float* __restrict__ emb, const float* __restrict__ w_ih,
                               const float* __restrict__ w_hh, const float* __restrict__ w_out,
                               char* __restrict__ ws) {
  f16* wpack = (f16*)(ws + OFF_WPACK);
  f16* wout  = (f16*)(ws + OFF_WOUT);
  f16* embh  = (f16*)(ws + OFF_EMB);
  const int NW = 3*32*65536;
  const int TOT = NW + 40960 + VOC*HID;
  for (int e = blockIdx.x*blockDim.x + threadIdx.x; e < TOT; e += gridDim.x*blockDim.x) {
    if (e < NW) {
      int l = e >> 21, rem = e & 0x1FFFFF;
      int g = rem >> 16, idx = rem & 0xFFFF;
      int gt = idx >> 14, kc = (idx >> 9) & 31, lane = (idx >> 3) & 63, jj = idx & 7;
      int n = lane & 15, q = lane >> 4;
      int k = kc*32 + q*8 + jj, d = g*16 + n;
      int row = (gt==0) ? d : (gt==1) ? 512+d : 1024+d;
      float f = (k < 512) ? w_ih[((size_t)(l*1536+row)<<9) + k]
                          : w_hh[((size_t)(l*1536+row)<<9) + (k-512)];
      f16 h;
      if (gt < 3) h = (f16)f;
      else { f16 hi = (f16)f; h = (f16)((f - (float)hi)*2048.0f); }
      wpack[e] = h;
    } else if (e < NW + 40960) {
      int idx = e - NW;
      int vt = idx >> 13, r2 = idx & 8191;
      int kc = r2 >> 9, lane = (r2 >> 3) & 63, jj = r2 & 7;
      int n = lane & 15, q = lane >> 4;
      int v = vt*16 + n, k = kc*32 + q*8 + jj;
      wout[idx] = (v < VOC) ? (f16)w_out[((size_t)v<<9) + k] : (f16)0.0f;
    } else {
      int idx = e - NW - 40960;
      embh[idx] = (f16)emb[idx];
    }
  }
}

// keep-alive: pin 4 A-fragments so MFMAs can't hoist above the preceding vmcnt wait
#define KEEP4(K0) asm volatile("" : "+v"(afr[K0]), "+v"(afr[K0+1]), "+v"(afr[K0+2]), "+v"(afr[K0+3]))

// x-part chunk (kc in [K0,K0+4), K0 < 16): consume after counted vmcnt wait
#define XCHUNK(K0, NW_) \
  asm volatile("s_waitcnt vmcnt(" #NW_ ")" ::: "memory"); \
  KEEP4(K0); \
  _Pragma("unroll") \
  for (int kc = K0; kc < K0+4; ++kc) { \
    f16x8 wnh = *(const f16x8*)(wlds + (((2*32 + kc)*64 + lane) << 3)); \
    f16x8 wnl = *(const f16x8*)(wlds + (((3*32 + kc)*64 + lane) << 3)); \
    ar   = __builtin_amdgcn_mfma_f32_16x16x32_f16(afr[kc], wr[kc], ar,   0, 0, 0); \
    az   = __builtin_amdgcn_mfma_f32_16x16x32_f16(afr[kc], wz[kc], az,   0, 0, 0); \
    anxh = __builtin_amdgcn_mfma_f32_16x16x32_f16(afr[kc], wnh,    anxh, 0, 0, 0); \
    anxl = __builtin_amdgcn_mfma_f32_16x16x32_f16(afr[kc], wnl,    anxl, 0, 0, 0); \
  }

// h-part chunk (kc in [K0,K0+4), K0 >= 16)
#define HCHUNK(K0, NW_) \
  asm volatile("s_waitcnt vmcnt(" #NW_ ")" ::: "memory"); \
  KEEP4(K0); \
  _Pragma("unroll") \
  for (int kc = K0; kc < K0+4; ++kc) { \
    f16x8 wnh = *(const f16x8*)(wlds + (((2*32 + kc)*64 + lane) << 3)); \
    f16x8 wnl = *(const f16x8*)(wlds + (((3*32 + kc)*64 + lane) << 3)); \
    ar   = __builtin_amdgcn_mfma_f32_16x16x32_f16(afr[kc], wr[kc], ar,   0, 0, 0); \
    az   = __builtin_amdgcn_mfma_f32_16x16x32_f16(afr[kc], wz[kc], az,   0, 0, 0); \
    anhh = __builtin_amdgcn_mfma_f32_16x16x32_f16(afr[kc], wnh,    anhh, 0, 0, 0); \
    anhl = __builtin_amdgcn_mfma_f32_16x16x32_f16(afr[kc], wnl,    anhl, 0, 0, 0); \
  }

// Persistent kernel, 212 WGs x 256 threads — r5 protocol + transposed ring, restructured so
// loads leave the serial recurrence chain:
//  phase A: poll upstream/backpressure -> issue x loads (no wait)
//  phase B: poll self WHILE x flies    -> issue h loads (no wait)
//  x-GEMM on counted vmcnt(28..16) — h loads still in flight behind it
//  h-GEMM on counted vmcnt(12..0)
__global__ void __launch_bounds__(256) rnn_kernel(const int* __restrict__ xseq,
                           const float* __restrict__ bias, const float* __restrict__ bias_n,
                           const float* __restrict__ b_out, float* __restrict__ out,
                           char* __restrict__ ws) {
  int* F = (int*)(ws + OFF_READY);
  f16* hring = (f16*)(ws + OFF_HRING);                // [3][8][2][64][64][8] transposed
  const int wg = blockIdx.x;
  const int tid = threadIdx.x;
  const int lane = tid & 63, wv = tid >> 6;
  const int quad = lane >> 4, nlane = lane & 15;

  __shared__ __align__(16) f16 wlds[65536];           // 131,072 B
  __shared__ __align__(16) f16 wolds[8192];           // 16,384 B
  __shared__ __align__(16) f16 hstage[64*24];         // 3,072 B (stride 24 f16 = 48B rows)

  if (wg < NLWG) {
    const int l = wg / 64, r = wg % 64, g = r >> 1, bh = r & 1;
    {
      const f16x8* src = (const f16x8*)((const f16*)(ws + OFF_WPACK) + ((size_t)(l*32+g) << 16));
      f16x8* dst = (f16x8*)wlds;
      for (int i = tid; i < 8192; i += 256) dst[i] = src[i];
    }
    const int j = g*16 + nlane;
    const float br  = bias[l*1536 + j];
    const float bz  = bias[l*1536 + 512 + j];
    const float bin = bias[l*1536 + 1024 + j];
    const float bn  = bias_n[l*512 + j];
    const int bm = bh*64 + wv*16 + nlane;             // A-operand batch row (for l==0 x gather)
    // per-lane offset into a transposed (l,slot,bh) half: [d8=kc*4+quad][row=wv*16+nlane][8]
    const int tofs = quad*512 + (wv*16 + nlane)*8;    // + kc*2048 per kc

    // poll pointers: phase A (upstream, wv0 lanes>=32; back-pressure, wv1);
    // phase B (self, wv0 lanes<32)
    const int* selfp = F + (l*64 + bh*32 + (lane & 31))*FPAD;
    const int* upp   = (l > 0) ? (F + ((l-1)*64 + bh*32 + (lane & 31))*FPAD) : F;
    const int* bpp = F; int bpact = 0;
    if (wv == 1) {
      if (l < 2) { if (lane < 32) { bpp = F + ((l+1)*64 + bh*32 + lane)*FPAD; bpact = 1; } }
      else       { if (lane < 10) { bpp = F + (192 + bh*10 + lane)*FPAD;      bpact = 1; } }
    }
    __syncthreads();
    // register-resident B-frags for r and z gates; conflict-free reads
    f16x8 wr[32], wz[32];
#pragma unroll
    for (int kc = 0; kc < 32; ++kc) {
      wr[kc] = *(const f16x8*)(wlds + (((0*32 + kc)*64 + lane) << 3));
      wz[kc] = *(const f16x8*)(wlds + (((1*32 + kc)*64 + lane) << 3));
    }
    const f16* embh = (const f16*)(ws + OFF_EMB);
    unsigned short hprev[4] = {0, 0, 0, 0};           // h(t-1) for this thread's (row, col) — f16 bits

    for (int t = 0; t < T_STEPS; ++t) {
      // ---- phase A: upstream readiness (x-input) + downstream back-pressure ----
      if (wv == 0) {
        if (l > 0 && lane >= 32) {
          const int tgt = t + 1;
          int spins = 0;
          while (1) {
            int v = __hip_atomic_load(upp, __ATOMIC_RELAXED, __HIP_MEMORY_SCOPE_AGENT);
            if (__all(v >= tgt)) break;
            if (++spins > (1 << 22)) break;           // hang-safety: fail visibly, not forever
            __builtin_amdgcn_s_sleep(1);
          }
        }
      } else if (wv == 1) {
        const int tgt = t - (DRING-1);
        int spins = 0;
        while (1) {
          int v = 0x7FFFFFFF;
          if (bpact) v = __hip_atomic_load(bpp, __ATOMIC_RELAXED, __HIP_MEMORY_SCOPE_AGENT);
          if (__all(v >= tgt)) break;
          if (++spins > (1 << 22)) break;
          __builtin_amdgcn_s_sleep(1);
        }
      }
      __syncthreads();                                // B1: x-input ready

      const int slot_w = t & (DRING-1), slot_r = (t + DRING - 1) & (DRING-1);
      f16x8 afr[32];
      // issue x loads (no wait) — they fly during the self-poll
      if (l == 0) {
        int idx = xseq[bm*T_STEPS + t];
        const f16* xr = embh + (size_t)idx*HID + quad*8;   // immutable: plain cached loads
#pragma unroll
        for (int kc = 0; kc < 16; ++kc) afr[kc] = ld16_pl(xr + kc*32);
      } else {
        const f16* xr = hring + (size_t)(((l-1)*DRING + slot_w)*2 + bh)*HHALF + tofs;
#pragma unroll
        for (int kc = 0; kc < 16; ++kc) afr[kc] = ld16_sc(xr + kc*2048);
      }
      // ---- phase B: self h(t-1) readiness, overlapped with x-load flight ----
      if (wv == 0 && lane < 32) {
        int spins = 0;
        while (1) {
          int v = __hip_atomic_load(selfp, __ATOMIC_RELAXED, __HIP_MEMORY_SCOPE_AGENT);
          if (__all(v >= t)) break;
          if (++spins > (1 << 22)) break;
          __builtin_amdgcn_s_sleep(1);
        }
      }
      __syncthreads();                                // B2: self h(t-1) visible
      // issue h loads (no wait) — they fly during the x-GEMM
      {
        const f16* hrk = hring + (size_t)((l*DRING + slot_r)*2 + bh)*HHALF + tofs;
#pragma unroll
        for (int kc = 0; kc < 16; ++kc) afr[16 + kc] = ld16_sc(hrk + kc*2048);
      }

      f32x4 ar{0,0,0,0}, az{0,0,0,0}, anxh{0,0,0,0}, anxl{0,0,0,0}, anhh{0,0,0,0}, anhl{0,0,0,0};
      XCHUNK(0, 28)  XCHUNK(4, 24)  XCHUNK(8, 20)   XCHUNK(12, 16)
      HCHUNK(16, 12) HCHUNK(20, 8)  HCHUNK(24, 4)   HCHUNK(28, 0)

      // epilogue: D layout col(lane&15)=dim j, row_local(wv*16+quad*4+i)=batch (within bh half)
#pragma unroll
      for (int i = 0; i < 4; ++i) {
        float rr = sigmoidf_(ar[i] + br);
        float zz = sigmoidf_(az[i] + bz);
        float hn = anhh[i] + anhl[i]*(1.0f/2048.0f) + bn;
        float nn = tanhf_(anxh[i] + anxl[i]*(1.0f/2048.0f) + bin + rr*hn);
        union { unsigned short u; f16 h; } cr; cr.u = hprev[i];
        float hv = nn + zz*((float)cr.h - nn);
        union { f16 h; unsigned short u; } cw; cw.h = (f16)hv;
        hprev[i] = cw.u;
        hstage[(wv*16 + quad*4 + i)*24 + nlane] = cw.h;   // LDS transpose stage
      }
      __syncthreads();
      // h stores, transposed layout: 128 threads -> two 1KB contiguous chunks (full lines)
      if (tid < 128) {
        int d8i = tid >> 6, row = tid & 63;
        f16x8 v8 = *(const f16x8*)(hstage + row*24 + d8i*8);
        f16* hw = hring + (size_t)((l*DRING + slot_w)*2 + bh)*HHALF
                        + (size_t)(2*g + d8i)*512 + row*8;
        st16_sc1(hw, v8);
      }
      asm volatile("s_waitcnt vmcnt(0)" ::: "memory"); // sc1 stores reached coherence point
      __syncthreads();
      if (tid == 0)
        __hip_atomic_store(F + (l*64 + bh*32 + g)*FPAD, t + 1,
                           __ATOMIC_RELAXED, __HIP_MEMORY_SCOPE_AGENT);
    }
  } else if (wg < NLWG + NPWG) {
    const int p = wg - NLWG, bt = p / 5, vt = p % 5, half = bt >> 1;
    {
      const f16x8* src = (const f16x8*)((const f16*)(ws + OFF_WOUT) + vt*8192);
      f16x8* dst = (f16x8*)wolds;
      for (int i = tid; i < 1024; i += 256) dst[i] = src[i];
    }
    const int v = vt*16 + nlane;
    const float bo = (v < VOC) ? b_out[v] : 0.0f;
    __syncthreads();
    for (int t = 0; t < T_STEPS; ++t) {
      if (wv == 0) {
        const int tgt = t + 1;
        int spins = 0;
        while (1) {
          int vv = 0x7FFFFFFF;
          if (lane < 32) vv = __hip_atomic_load(F + (2*64 + half*32 + lane)*FPAD,
                                                __ATOMIC_RELAXED, __HIP_MEMORY_SCOPE_AGENT);
          if (__all(vv >= tgt)) break;
          if (++spins > (1 << 22)) break;
          __builtin_amdgcn_s_sleep(1);
        }
      }
      __syncthreads();
      if (wv < 2) {
        const int row_abs = bt*32 + wv*16 + nlane;     // absolute batch row 0..127
        const int bh2 = row_abs >> 6, rih = row_abs & 63;
        const f16* hrow = hring + (size_t)((2*DRING + (t & (DRING-1)))*2 + bh2)*HHALF
                                + quad*512 + rih*8;
        f16x8 af[16];
#pragma unroll
        for (int kc = 0; kc < 16; ++kc) af[kc] = ld16_sc(hrow + kc*2048);
        asm volatile("s_waitcnt vmcnt(0)" ::: "memory");
#pragma unroll
        for (int kc = 0; kc < 16; ++kc) asm volatile("" : "+v"(af[kc]));
        f32x4 acc{0,0,0,0};
#pragma unroll
        for (int kc = 0; kc < 16; ++kc) {
          f16x8 w = *(const f16x8*)(wolds + ((kc*64 + lane) << 3));
          acc = __builtin_amdgcn_mfma_f32_16x16x32_f16(af[kc], w, acc, 0, 0, 0);
        }
        if (v < VOC) {
          const int bmb = bt*32 + wv*16;
#pragma unroll
          for (int i = 0; i < 4; ++i) {
            int bidx = bmb + quad*4 + i;
            out[((size_t)bidx*T_STEPS + t)*VOC + v] = acc[i] + bo;
          }
        }
      }
      __syncthreads();
      if (tid == 0)
        __hip_atomic_store(F + (192 + p)*FPAD, t + 1, __ATOMIC_RELAXED, __HIP_MEMORY_SCOPE_AGENT);
    }
  }
}

extern "C" void kernel_launch(void* const* d_in, const int* in_sizes, int n_in,
                              void* d_out, int out_size, void* d_ws, size_t ws_size,
                              hipStream_t stream) {
  const int*   xseq  = (const int*)d_in[0];
  const float* emb   = (const float*)d_in[1];
  const float* w_ih  = (const float*)d_in[2];
  const float* w_hh  = (const float*)d_in[3];
  const float* b     = (const float*)d_in[4];
  const float* b_n   = (const float*)d_in[5];
  const float* w_out = (const float*)d_in[6];
  const float* b_out = (const float*)d_in[7];
  char* ws = (char*)d_ws;

  // zero flags + h ring (h[-1] = 0 initial state); re-done every call
  (void)hipMemsetAsync(d_ws, 0, OFF_HRING + HRING_BYTES, stream);
  hipLaunchKernelGGL(convert_kernel, dim3(4096), dim3(256), 0, stream,
                     emb, w_ih, w_hh, w_out, ws);
  hipLaunchKernelGGL(rnn_kernel, dim3(NLWG + NPWG), dim3(256), 0, stream,
                     xseq, b, b_n, b_out, (float*)d_out, ws);
}